// Round 5
// baseline (926.438 us; speedup 1.0000x reference)
//
#include <hip/hip_runtime.h>
#include <cstdint>
#include <cstddef>

// Problem constants: B=2, R=4096, P=64, CD=1, CF=64, D=16, H=256, W=256
constexpr int kB  = 2;
constexpr int kR  = 4096;
constexpr int kP  = 64;
constexpr int kCF = 64;
constexpr int kD  = 16;
constexpr int kH  = 256;
constexpr int kW  = 256;
constexpr int kHW = kH * kW;               // 65536
constexpr size_t kDHW = (size_t)kD * kHW;  // 1048576

// --- shared trilinear setup: 8 clamped voxel offsets + border-masked weights ---
struct Corners { int vox[8]; float w[8]; };

__device__ __forceinline__ Corners make_corners(float px, float py, float pz) {
    // align_corners=True mapping (x->W, y->H, z->D)
    const float fx = (px + 1.0f) * 0.5f * (float)(kW - 1);
    const float fy = (py + 1.0f) * 0.5f * (float)(kH - 1);
    const float fz = (pz + 1.0f) * 0.5f * (float)(kD - 1);
    const float x0f = floorf(fx), y0f = floorf(fy), z0f = floorf(fz);
    const float tx = fx - x0f, ty = fy - y0f, tz = fz - z0f;
    const int x0 = (int)x0f, y0 = (int)y0f, z0 = (int)z0f;

    const float wxv[2] = {1.0f - tx, tx};
    const float wyv[2] = {1.0f - ty, ty};
    const float wzv[2] = {1.0f - tz, tz};
    const int xs[2] = {x0, x0 + 1};
    const int ys[2] = {y0, y0 + 1};
    const int zs[2] = {z0, z0 + 1};

    Corners c;
    #pragma unroll
    for (int iz = 0; iz < 2; ++iz) {
        const int zi = zs[iz];
        const bool vz = (zi >= 0) & (zi < kD);
        const int zb = min(max(zi, 0), kD - 1) * kHW;
        #pragma unroll
        for (int iy = 0; iy < 2; ++iy) {
            const int yi = ys[iy];
            const bool vy = (yi >= 0) & (yi < kH);
            const int zyb = zb + min(max(yi, 0), kH - 1) * kW;
            const float wzy = wzv[iz] * wyv[iy];
            #pragma unroll
            for (int ix = 0; ix < 2; ++ix) {
                const int xi = xs[ix];
                const bool vx = (xi >= 0) & (xi < kW);
                const int k = iz * 4 + iy * 2 + ix;
                c.vox[k] = zyb + min(max(xi, 0), kW - 1);
                c.w[k]   = wzy * wxv[ix] * ((vz & vy & vx) ? 1.0f : 0.0f);
            }
        }
    }
    return c;
}

// ---------------------------------------------------------------------------
// Pass 1: transpose features [B,64,D,H,W] -> [B,D,H,W,64] (channel-last)
// ---------------------------------------------------------------------------
__global__ __launch_bounds__(256) void transpose_cf(
    const float* __restrict__ features,  // [B,64,D,H,W]
    float* __restrict__ ftr)             // [B,D,H,W,64]
{
    __shared__ float tile[64][65];       // +1 pad: both sides exact 2-way (free, m136)
    const int bid = blockIdx.x;          // B*D*H*(W/64) = 32768
    const int xt  = bid & 3;
    const int y   = (bid >> 2) & 255;
    const int z   = (bid >> 10) & 15;
    const int b   = bid >> 14;
    const int x0  = xt * 64;
    const int t   = threadIdx.x;
    const int sub = (t & 15) * 4;        // float4 offset within a 64-row
    const int rr  = t >> 4;              // 0..15

    const size_t rbase = (size_t)b * 64 * kDHW + (size_t)z * kHW + (size_t)y * kW + x0;
    #pragma unroll
    for (int i = 0; i < 4; ++i) {
        const int c = rr + 16 * i;
        const float4 v = *(const float4*)(features + rbase + (size_t)c * kDHW + sub);
        tile[c][sub + 0] = v.x; tile[c][sub + 1] = v.y;
        tile[c][sub + 2] = v.z; tile[c][sub + 3] = v.w;
    }
    __syncthreads();

    float* dst0 = ftr + (((size_t)(b * kD + z) * kH + y) * kW + x0) * 64;
    #pragma unroll
    for (int i = 0; i < 4; ++i) {
        const int x = rr + 16 * i;
        float4 v;
        v.x = tile[sub + 0][x]; v.y = tile[sub + 1][x];
        v.z = tile[sub + 2][x]; v.w = tile[sub + 3][x];
        *(float4*)(dst0 + (size_t)x * 64 + sub) = v;
    }
}

// ---------------------------------------------------------------------------
// Pass 2: sampler on channel-last features. One wave per ray.
//   Feature phase: 16-lane group g owns point p+g; lane quad (lane&15)*4 ->
//   4 channels, float4 gathers (16 B/lane), 1 KiB contiguous wave stores.
//   Zero-weight corners (outside the volume) skip the load entirely.
//   Density phase: lane p owns point p (L2-hot 8 MB volume).
// ---------------------------------------------------------------------------
__global__ __launch_bounds__(256) void sample_tr(
    const float* __restrict__ density,   // [B,1,D,H,W]
    const float* __restrict__ ftr,       // [B,D,H,W,64]
    const float* __restrict__ w2l,
    const float* __restrict__ origins,
    const float* __restrict__ dirs,
    const float* __restrict__ lengths,
    float* __restrict__ out_d,           // [B,R,P]
    float* __restrict__ out_f)           // [B,R,P,64]
{
    const int lane = threadIdx.x & 63;
    const int wv   = threadIdx.x >> 6;
    const int ray  = blockIdx.x * 4 + wv;
    const int b    = ray >> 12;

    const float* M   = w2l + (size_t)b * 16;
    const float* org = origins + (size_t)ray * 3;
    const float* dir = dirs    + (size_t)ray * 3;
    const float ox = org[0], oy = org[1], oz = org[2];
    const float dx = dir[0], dy = dir[1], dz = dir[2];

    // row-vector convention: o_loc[j] = sum_i o[i]*M[i][j] + M[3][j]
    const float olx = ox*M[0] + oy*M[4] + oz*M[8]  + M[12];
    const float oly = ox*M[1] + oy*M[5] + oz*M[9]  + M[13];
    const float olz = ox*M[2] + oy*M[6] + oz*M[10] + M[14];
    const float dlx = dx*M[0] + dy*M[4] + dz*M[8];
    const float dly = dx*M[1] + dy*M[5] + dz*M[9];
    const float dlz = dx*M[2] + dy*M[6] + dz*M[10];

    const float* db = density + (size_t)b * kDHW;
    const float tlen = lengths[(size_t)ray * kP + lane];   // lane p holds t_p

    // --- density phase ---
    {
        const float t  = tlen;
        const Corners c = make_corners(olx + dlx * t, oly + dly * t, olz + dlz * t);
        float accd = 0.0f;
        #pragma unroll
        for (int k = 0; k < 8; ++k)
            if (c.w[k] != 0.0f) accd += c.w[k] * db[c.vox[k]];  // predicated: no traffic if w==0
        out_d[(size_t)ray * kP + lane] = accd;                  // coalesced 256 B
    }

    // --- feature phase: 4 points per wave iteration ---
    const int grp = lane >> 4;           // 0..3 : point offset within quad
    const int c4  = (lane & 15) * 4;     // this lane's 4 channels
    const float* fb = ftr + (size_t)b * kDHW * 64 + c4;
    float* ofr = out_f + (size_t)ray * kP * 64 + c4;

    for (int pg = 0; pg < kP / 4; ++pg) {
        const int p = pg * 4 + grp;
        const float t  = __shfl(tlen, p);
        const Corners c = make_corners(olx + dlx * t, oly + dly * t, olz + dlz * t);
        float4 acc = {0.f, 0.f, 0.f, 0.f};
        #pragma unroll
        for (int k = 0; k < 8; ++k) {
            const float w = c.w[k];
            if (w != 0.0f) {             // OOB corner: skip the 256 B group burst
                const float4 v = *(const float4*)(fb + (size_t)c.vox[k] * 64);
                acc.x += w * v.x; acc.y += w * v.y;
                acc.z += w * v.z; acc.w += w * v.w;
            }
        }
        *(float4*)(ofr + (size_t)p * 64) = acc;            // wave: 1 KiB contiguous
    }
}

// ---------------------------------------------------------------------------
// Fallback: direct-layout sampler (used only if d_ws < 537 MB)
// ---------------------------------------------------------------------------
__global__ __launch_bounds__(256) void grid_sampler_direct(
    const float* __restrict__ density,
    const float* __restrict__ features,  // [B,64,D,H,W]
    const float* __restrict__ w2l,
    const float* __restrict__ origins,
    const float* __restrict__ dirs,
    const float* __restrict__ lengths,
    float* __restrict__ out_d,
    float* __restrict__ out_f)
{
    const int lane = threadIdx.x & 63;
    const int wv   = threadIdx.x >> 6;
    const int ray  = blockIdx.x * 4 + wv;
    const int b    = ray >> 12;

    const float* M   = w2l + (size_t)b * 16;
    const float* org = origins + (size_t)ray * 3;
    const float* dir = dirs    + (size_t)ray * 3;
    const float ox = org[0], oy = org[1], oz = org[2];
    const float dx = dir[0], dy = dir[1], dz = dir[2];

    const float olx = ox*M[0] + oy*M[4] + oz*M[8]  + M[12];
    const float oly = ox*M[1] + oy*M[5] + oz*M[9]  + M[13];
    const float olz = ox*M[2] + oy*M[6] + oz*M[10] + M[14];
    const float dlx = dx*M[0] + dy*M[4] + dz*M[8];
    const float dly = dx*M[1] + dy*M[5] + dz*M[9];
    const float dlz = dx*M[2] + dy*M[6] + dz*M[10];

    const float* fb = features + (size_t)b * kCF * kDHW + (size_t)lane * kDHW;
    const float* db = density  + (size_t)b * kDHW;
    const float tlen = lengths[(size_t)ray * kP + lane];

    {
        const float t  = tlen;
        const Corners c = make_corners(olx + dlx * t, oly + dly * t, olz + dlz * t);
        float accd = 0.0f;
        #pragma unroll
        for (int k = 0; k < 8; ++k)
            if (c.w[k] != 0.0f) accd += c.w[k] * db[c.vox[k]];
        out_d[(size_t)ray * kP + lane] = accd;
    }

    float* ofr = out_f + (size_t)ray * kP * 64 + lane;
    for (int p = 0; p < kP; ++p) {
        const float t  = __shfl(tlen, p);
        const Corners c = make_corners(olx + dlx * t, oly + dly * t, olz + dlz * t);
        float acc = 0.0f;
        #pragma unroll
        for (int k = 0; k < 8; ++k)
            if (c.w[k] != 0.0f) acc += c.w[k] * fb[c.vox[k]];
        ofr[(size_t)p * 64] = acc;
    }
}

extern "C" void kernel_launch(void* const* d_in, const int* in_sizes, int n_in,
                              void* d_out, int out_size, void* d_ws, size_t ws_size,
                              hipStream_t stream) {
    const float* density  = (const float*)d_in[0];
    const float* features = (const float*)d_in[1];
    const float* w2l      = (const float*)d_in[2];
    const float* origins  = (const float*)d_in[3];
    const float* dirs     = (const float*)d_in[4];
    const float* lengths  = (const float*)d_in[5];

    float* out_d = (float*)d_out;                    // [B,R,P]
    float* out_f = out_d + (size_t)kB * kR * kP;     // [B,R,P,64]

    const size_t need = (size_t)kB * kDHW * 64 * sizeof(float);  // 536,870,912 B

    if (ws_size >= need) {
        float* ftr = (float*)d_ws;                   // [B,D,H,W,64]
        hipLaunchKernelGGL(transpose_cf, dim3(kB * kD * kH * (kW / 64)), dim3(256),
                           0, stream, features, ftr);
        hipLaunchKernelGGL(sample_tr, dim3(kB * kR / 4), dim3(256), 0, stream,
                           density, ftr, w2l, origins, dirs, lengths, out_d, out_f);
    } else {
        hipLaunchKernelGGL(grid_sampler_direct, dim3(kB * kR / 4), dim3(256), 0, stream,
                           density, features, w2l, origins, dirs, lengths, out_d, out_f);
    }
}

// Round 10
// 812.457 us; speedup vs baseline: 1.1403x; 1.1403x over previous
//
#include <hip/hip_runtime.h>
#include <hip/hip_fp16.h>
#include <cstdint>
#include <cstddef>

// Problem constants: B=2, R=4096, P=64, CD=1, CF=64, D=16, H=256, W=256
constexpr int kB  = 2;
constexpr int kR  = 4096;
constexpr int kP  = 64;
constexpr int kCF = 64;
constexpr int kD  = 16;
constexpr int kH  = 256;
constexpr int kW  = 256;
constexpr int kHW = kH * kW;               // 65536
constexpr size_t kDHW = (size_t)kD * kHW;  // 1048576

// clang native vectors (accepted by __builtin_nontemporal_*)
typedef float    v4f __attribute__((ext_vector_type(4)));
typedef uint32_t v4u __attribute__((ext_vector_type(4)));

// --- trilinear setup: 8 clamped voxel offsets + border-masked weights -------
// status: 2 = all 8 corners valid, 0 = all invalid (fully outside), 1 = partial
struct Corners { int vox[8]; float w[8]; int status; };

__device__ __forceinline__ Corners make_corners(float px, float py, float pz) {
    // align_corners=True mapping (x->W, y->H, z->D)
    const float fx = (px + 1.0f) * 0.5f * (float)(kW - 1);
    const float fy = (py + 1.0f) * 0.5f * (float)(kH - 1);
    const float fz = (pz + 1.0f) * 0.5f * (float)(kD - 1);
    const float x0f = floorf(fx), y0f = floorf(fy), z0f = floorf(fz);
    const float tx = fx - x0f, ty = fy - y0f, tz = fz - z0f;
    const int x0 = (int)x0f, y0 = (int)y0f, z0 = (int)z0f;

    const float wxv[2] = {1.0f - tx, tx};
    const float wyv[2] = {1.0f - ty, ty};
    const float wzv[2] = {1.0f - tz, tz};
    const int xs[2] = {x0, x0 + 1};
    const int ys[2] = {y0, y0 + 1};
    const int zs[2] = {z0, z0 + 1};

    Corners c;
    #pragma unroll
    for (int iz = 0; iz < 2; ++iz) {
        const int zi = zs[iz];
        const bool vz = (zi >= 0) & (zi < kD);
        const int zb = min(max(zi, 0), kD - 1) * kHW;
        #pragma unroll
        for (int iy = 0; iy < 2; ++iy) {
            const int yi = ys[iy];
            const bool vy = (yi >= 0) & (yi < kH);
            const int zyb = zb + min(max(yi, 0), kH - 1) * kW;
            const float wzy = wzv[iz] * wyv[iy];
            #pragma unroll
            for (int ix = 0; ix < 2; ++ix) {
                const int xi = xs[ix];
                const bool vx = (xi >= 0) & (xi < kW);
                const int k = iz * 4 + iy * 2 + ix;
                c.vox[k] = zyb + min(max(xi, 0), kW - 1);
                c.w[k]   = wzy * wxv[ix] * ((vz & vy & vx) ? 1.0f : 0.0f);
            }
        }
    }
    const bool allIn  = (x0 >= 0) & (x0 <= kW - 2) & (y0 >= 0) & (y0 <= kH - 2)
                      & (z0 >= 0) & (z0 <= kD - 2);
    const bool allOut = (x0 < -1) | (x0 > kW - 1) | (y0 < -1) | (y0 > kH - 1)
                      | (z0 < -1) | (z0 > kD - 1);
    c.status = allIn ? 2 : (allOut ? 0 : 1);
    return c;
}

// ---------------------------------------------------------------------------
// Pass 1: transpose+compress features [B,64,D,H,W] f32 -> [B,D,H,W,64] f16
// Input loads are non-temporal (read-once stream; don't evict the f16 volume).
// ---------------------------------------------------------------------------
__global__ __launch_bounds__(256) void transpose_cf(
    const float* __restrict__ features,  // [B,64,D,H,W] f32
    __half* __restrict__ ftr)            // [B,D,H,W,64] f16
{
    __shared__ float tile[64][65];       // +1 pad: both sides ~2-way (free, m136)
    const int bid = blockIdx.x;          // B*D*H*(W/64) = 32768
    const int xt  = bid & 3;
    const int y   = (bid >> 2) & 255;
    const int z   = (bid >> 10) & 15;
    const int b   = bid >> 14;
    const int x0  = xt * 64;
    const int t   = threadIdx.x;
    const int sub = (t & 15) * 4;        // 4-element offset within a 64-row
    const int rr  = t >> 4;              // 0..15

    const size_t rbase = (size_t)b * 64 * kDHW + (size_t)z * kHW + (size_t)y * kW + x0;
    #pragma unroll
    for (int i = 0; i < 4; ++i) {
        const int c = rr + 16 * i;
        const v4f v = __builtin_nontemporal_load(
            (const v4f*)(features + rbase + (size_t)c * kDHW + sub));
        tile[c][sub + 0] = v.x; tile[c][sub + 1] = v.y;
        tile[c][sub + 2] = v.z; tile[c][sub + 3] = v.w;
    }
    __syncthreads();

    const size_t voxbase = (((size_t)(b * kD + z) * kH + y) * kW + x0);
    #pragma unroll
    for (int i = 0; i < 4; ++i) {
        const int x = rr + 16 * i;       // x within tile; channel = sub..sub+3
        union { __half2 h[2]; uint2 u; } pk;
        pk.h[0] = __floats2half2_rn(tile[sub + 0][x], tile[sub + 1][x]);
        pk.h[1] = __floats2half2_rn(tile[sub + 2][x], tile[sub + 3][x]);
        *(uint2*)(ftr + (voxbase + x) * 64 + sub) = pk.u;   // cacheable: read next pass
    }
}

// ---------------------------------------------------------------------------
// Pass 2: sampler. One wave per ray.
//   Feature phase: 8-lane group g owns point pg*8+g; lane covers 8 channels
//   (f16, 16 B loads). Wave-uniform fast paths: all-inside -> unguarded loads
//   (full MLP); all-outside -> skip; boundary shell -> per-corner guards.
//   Output stores non-temporal (write-once; keep L2/L3 for the gather set).
//   Density phase: lane p owns point p (f32 volume, L2-hot).
// ---------------------------------------------------------------------------
__global__ __launch_bounds__(256) void sample_tr(
    const float* __restrict__ density,   // [B,1,D,H,W] f32
    const __half* __restrict__ ftr,      // [B,D,H,W,64] f16
    const float* __restrict__ w2l,
    const float* __restrict__ origins,
    const float* __restrict__ dirs,
    const float* __restrict__ lengths,
    float* __restrict__ out_d,           // [B,R,P]
    float* __restrict__ out_f)           // [B,R,P,64]
{
    const int lane = threadIdx.x & 63;
    const int wv   = threadIdx.x >> 6;
    const int ray  = blockIdx.x * 4 + wv;
    const int b    = ray >> 12;

    const float* M   = w2l + (size_t)b * 16;
    const float* org = origins + (size_t)ray * 3;
    const float* dir = dirs    + (size_t)ray * 3;
    const float ox = org[0], oy = org[1], oz = org[2];
    const float dx = dir[0], dy = dir[1], dz = dir[2];

    // row-vector convention: o_loc[j] = sum_i o[i]*M[i][j] + M[3][j]
    const float olx = ox*M[0] + oy*M[4] + oz*M[8]  + M[12];
    const float oly = ox*M[1] + oy*M[5] + oz*M[9]  + M[13];
    const float olz = ox*M[2] + oy*M[6] + oz*M[10] + M[14];
    const float dlx = dx*M[0] + dy*M[4] + dz*M[8];
    const float dly = dx*M[1] + dy*M[5] + dz*M[9];
    const float dlz = dx*M[2] + dy*M[6] + dz*M[10];

    const float* db = density + (size_t)b * kDHW;
    const float tlen = lengths[(size_t)ray * kP + lane];   // lane p holds t_p

    // --- density phase: lane p owns point p ---
    {
        const float t  = tlen;
        const Corners c = make_corners(olx + dlx * t, oly + dly * t, olz + dlz * t);
        float accd = 0.0f;
        if (c.status != 0) {
            #pragma unroll
            for (int k = 0; k < 8; ++k)
                if (c.w[k] != 0.0f) accd += c.w[k] * db[c.vox[k]];
        }
        __builtin_nontemporal_store(accd, out_d + (size_t)ray * kP + lane); // 256 B/wave
    }

    // --- feature phase: 8 points per wave iteration, 8 f16 channels/lane ---
    const int grp = lane >> 3;           // 0..7 : point offset within octet
    const int c8  = (lane & 7) * 8;      // this lane's 8 channels
    const __half* fb = ftr + (size_t)b * kDHW * 64 + c8;
    float* ofr = out_f + (size_t)ray * kP * 64 + c8;

    for (int pg = 0; pg < kP / 8; ++pg) {
        const int p = pg * 8 + grp;
        const float t  = __shfl(tlen, p);
        const Corners c = make_corners(olx + dlx * t, oly + dly * t, olz + dlz * t);
        float a0=0.f,a1=0.f,a2=0.f,a3=0.f,a4=0.f,a5=0.f,a6=0.f,a7=0.f;

        if (__all(c.status == 2)) {
            // fast path: all 8 corners valid for every point in flight
            #pragma unroll
            for (int k = 0; k < 8; ++k) {
                union { v4u u; __half2 h[4]; } U;
                U.u = *(const v4u*)(fb + (size_t)c.vox[k] * 64);     // 16 B/lane
                const float w = c.w[k];
                const float2 f0 = __half22float2(U.h[0]);
                const float2 f1 = __half22float2(U.h[1]);
                const float2 f2 = __half22float2(U.h[2]);
                const float2 f3 = __half22float2(U.h[3]);
                a0 += w * f0.x; a1 += w * f0.y; a2 += w * f1.x; a3 += w * f1.y;
                a4 += w * f2.x; a5 += w * f2.y; a6 += w * f3.x; a7 += w * f3.y;
            }
        } else if (!__all(c.status == 0)) {
            // boundary shell: per-corner guard (rare)
            #pragma unroll
            for (int k = 0; k < 8; ++k) {
                const float w = c.w[k];
                if (w != 0.0f) {
                    union { v4u u; __half2 h[4]; } U;
                    U.u = *(const v4u*)(fb + (size_t)c.vox[k] * 64);
                    const float2 f0 = __half22float2(U.h[0]);
                    const float2 f1 = __half22float2(U.h[1]);
                    const float2 f2 = __half22float2(U.h[2]);
                    const float2 f3 = __half22float2(U.h[3]);
                    a0 += w * f0.x; a1 += w * f0.y; a2 += w * f1.x; a3 += w * f1.y;
                    a4 += w * f2.x; a5 += w * f2.y; a6 += w * f3.x; a7 += w * f3.y;
                }
            }
        }
        // store: lane writes 32 B; 8-lane group = 256 B; wave = 2 KiB contiguous
        v4f s0; s0.x = a0; s0.y = a1; s0.z = a2; s0.w = a3;
        v4f s1; s1.x = a4; s1.y = a5; s1.z = a6; s1.w = a7;
        __builtin_nontemporal_store(s0, (v4f*)(ofr + (size_t)p * 64));
        __builtin_nontemporal_store(s1, (v4f*)(ofr + (size_t)p * 64 + 4));
    }
}

// ---------------------------------------------------------------------------
// Fallback: direct-layout f32 sampler (used only if d_ws too small)
// ---------------------------------------------------------------------------
__global__ __launch_bounds__(256) void grid_sampler_direct(
    const float* __restrict__ density,
    const float* __restrict__ features,  // [B,64,D,H,W]
    const float* __restrict__ w2l,
    const float* __restrict__ origins,
    const float* __restrict__ dirs,
    const float* __restrict__ lengths,
    float* __restrict__ out_d,
    float* __restrict__ out_f)
{
    const int lane = threadIdx.x & 63;
    const int wv   = threadIdx.x >> 6;
    const int ray  = blockIdx.x * 4 + wv;
    const int b    = ray >> 12;

    const float* M   = w2l + (size_t)b * 16;
    const float* org = origins + (size_t)ray * 3;
    const float* dir = dirs    + (size_t)ray * 3;
    const float ox = org[0], oy = org[1], oz = org[2];
    const float dx = dir[0], dy = dir[1], dz = dir[2];

    const float olx = ox*M[0] + oy*M[4] + oz*M[8]  + M[12];
    const float oly = ox*M[1] + oy*M[5] + oz*M[9]  + M[13];
    const float olz = ox*M[2] + oy*M[6] + oz*M[10] + M[14];
    const float dlx = dx*M[0] + dy*M[4] + dz*M[8];
    const float dly = dx*M[1] + dy*M[5] + dz*M[9];
    const float dlz = dx*M[2] + dy*M[6] + dz*M[10];

    const float* fb = features + (size_t)b * kCF * kDHW + (size_t)lane * kDHW;
    const float* db = density  + (size_t)b * kDHW;
    const float tlen = lengths[(size_t)ray * kP + lane];

    {
        const float t  = tlen;
        const Corners c = make_corners(olx + dlx * t, oly + dly * t, olz + dlz * t);
        float accd = 0.0f;
        if (c.status != 0) {
            #pragma unroll
            for (int k = 0; k < 8; ++k)
                if (c.w[k] != 0.0f) accd += c.w[k] * db[c.vox[k]];
        }
        out_d[(size_t)ray * kP + lane] = accd;
    }

    float* ofr = out_f + (size_t)ray * kP * 64 + lane;
    for (int p = 0; p < kP; ++p) {
        const float t  = __shfl(tlen, p);
        const Corners c = make_corners(olx + dlx * t, oly + dly * t, olz + dlz * t);
        float acc = 0.0f;
        if (c.status != 0) {
            #pragma unroll
            for (int k = 0; k < 8; ++k)
                if (c.w[k] != 0.0f) acc += c.w[k] * fb[c.vox[k]];
        }
        ofr[(size_t)p * 64] = acc;
    }
}

extern "C" void kernel_launch(void* const* d_in, const int* in_sizes, int n_in,
                              void* d_out, int out_size, void* d_ws, size_t ws_size,
                              hipStream_t stream) {
    const float* density  = (const float*)d_in[0];
    const float* features = (const float*)d_in[1];
    const float* w2l      = (const float*)d_in[2];
    const float* origins  = (const float*)d_in[3];
    const float* dirs     = (const float*)d_in[4];
    const float* lengths  = (const float*)d_in[5];

    float* out_d = (float*)d_out;                    // [B,R,P]
    float* out_f = out_d + (size_t)kB * kR * kP;     // [B,R,P,64]

    const size_t need = (size_t)kB * kDHW * 64 * sizeof(__half);  // 268,435,456 B

    if (ws_size >= need) {
        __half* ftr = (__half*)d_ws;                 // [B,D,H,W,64] f16
        hipLaunchKernelGGL(transpose_cf, dim3(kB * kD * kH * (kW / 64)), dim3(256),
                           0, stream, features, ftr);
        hipLaunchKernelGGL(sample_tr, dim3(kB * kR / 4), dim3(256), 0, stream,
                           density, ftr, w2l, origins, dirs, lengths, out_d, out_f);
    } else {
        hipLaunchKernelGGL(grid_sampler_direct, dim3(kB * kR / 4), dim3(256), 0, stream,
                           density, features, w2l, origins, dirs, lengths, out_d, out_f);
    }
}